// Round 1
// baseline (887.478 us; speedup 1.0000x reference)
//
#include <hip/hip_runtime.h>
#include <hip/hip_bf16.h>

// Problem constants
#define BATCH 128
#define TSTEPS 64
#define EMB 256
#define HID 512
#define GATES 2048   // 4*HID
#define NFEAT 2048
#define VOCAB 50000

typedef __bf16 bf16_t;
typedef __attribute__((ext_vector_type(8))) __bf16 bf16x8;
typedef __attribute__((ext_vector_type(4))) float f32x4;

#define MFMA16 __builtin_amdgcn_mfma_f32_16x16x32_bf16

// Fragment load: lane l -> row = row0 + (l&15), k = k0 + (l>>4)*8, 8 consecutive bf16 (16B).
// Any consistent bijective K-permutation guess is correct for GEMM as long as A and B match.
__device__ __forceinline__ bf16x8 frag16(const bf16_t* __restrict__ base, int row0, int stride,
                                         int k0, int lane) {
    return *(const bf16x8*)(base + (size_t)(row0 + (lane & 15)) * stride + k0 + ((lane >> 4) << 3));
}

__device__ __forceinline__ float sigm(float x) { return 1.f / (1.f + __expf(-x)); }
__device__ __forceinline__ float tanh_f(float x) { return 1.f - 2.f / (__expf(2.f * x) + 1.f); }

// ---------------- prep: convert weights to bf16, gather embeddings, zero state ----------------
__global__ __launch_bounds__(256) void k_prep(
    const float* __restrict__ Wih, const float* __restrict__ Whh, const float* __restrict__ Wout,
    const float* __restrict__ bih, const float* __restrict__ bhh,
    const int* __restrict__ m, const float* __restrict__ emb_tab,
    bf16_t* __restrict__ wih_b, bf16_t* __restrict__ whh_b, bf16_t* __restrict__ wout_b,
    float* __restrict__ biassum, bf16_t* __restrict__ emb_b,
    bf16_t* __restrict__ h0, bf16_t* __restrict__ h1, float* __restrict__ cbuf) {
    const int N1 = GATES * EMB;          // 524288  Wih
    const int N2 = GATES * HID;          // 1048576 Whh
    const int N3 = NFEAT * HID;          // 1048576 Wout
    const int N4 = GATES;                // 2048    bias sum
    const int N5 = BATCH * TSTEPS * EMB; // 2097152 gather
    const int N6 = BATCH * HID;          // 65536   h0
    const int N7 = BATCH * HID;          // h1
    const int N8 = BATCH * HID;          // c
    const long total = (long)N1 + N2 + N3 + N4 + N5 + N6 + N7 + N8;
    for (long i = (long)blockIdx.x * blockDim.x + threadIdx.x; i < total;
         i += (long)gridDim.x * blockDim.x) {
        long x = i;
        if (x < N1) { wih_b[x] = (bf16_t)Wih[x]; continue; } x -= N1;
        if (x < N2) { whh_b[x] = (bf16_t)Whh[x]; continue; } x -= N2;
        if (x < N3) { wout_b[x] = (bf16_t)Wout[x]; continue; } x -= N3;
        if (x < N4) { biassum[x] = bih[x] + bhh[x]; continue; } x -= N4;
        if (x < N5) {
            int e = (int)(x & (EMB - 1));
            int rt = (int)(x >> 8);            // rt = b*64 + t
            int tok = m[rt];
            emb_b[x] = (bf16_t)emb_tab[(size_t)tok * EMB + e];
            continue;
        } x -= N5;
        if (x < N6) { h0[x] = (bf16_t)0.f; continue; } x -= N6;
        if (x < N7) { h1[x] = (bf16_t)0.f; continue; } x -= N7;
        cbuf[x] = 0.f;
    }
}

// ---------------- x_proj GEMM: [8192,256] x [256->2048] -> xproj[t][b][g] (f32, +bias) --------
__global__ __launch_bounds__(256) void k_xproj(
    const bf16_t* __restrict__ A,     // emb_b [8192][256], row r = b*64+t
    const bf16_t* __restrict__ Wih,   // [2048][256]
    const float* __restrict__ biassum,
    float* __restrict__ xproj) {      // [64][128][2048]
    int lane = threadIdx.x & 63, w = threadIdx.x >> 6;
    int r0 = blockIdx.x * 32 + (w & 1) * 16;       // row tile (b,t)
    int g0 = blockIdx.y * 128 + (w >> 1) * 64;     // col tile
    f32x4 acc[4] = {};
    #pragma unroll
    for (int k = 0; k < EMB; k += 32) {
        bf16x8 a = frag16(A, r0, EMB, k, lane);
        #pragma unroll
        for (int t = 0; t < 4; t++) {
            bf16x8 b = frag16(Wih, g0 + 16 * t, EMB, k, lane);
            acc[t] = MFMA16(a, b, acc[t], 0, 0, 0);
        }
    }
    #pragma unroll
    for (int t = 0; t < 4; t++) {
        int g = g0 + 16 * t + (lane & 15);
        float bs = biassum[g];
        #pragma unroll
        for (int r = 0; r < 4; r++) {
            int row = r0 + ((lane >> 4) << 2) + r;     // = b*64 + t
            int tt = row & 63, bb = row >> 6;
            xproj[((size_t)tt * BATCH + bb) * GATES + g] = acc[t][r] + bs;
        }
    }
}

// ---------------- per-step: gates GEMM + fused LSTM cell ----------------
__global__ __launch_bounds__(256) void k_step(
    const bf16_t* __restrict__ hprev,  // [128][512] bf16
    bf16_t* __restrict__ hnext,        // [128][512] bf16
    float* __restrict__ cbuf,          // [128][512] f32
    const bf16_t* __restrict__ Whh,    // [2048][512] bf16
    const float* __restrict__ xp) {    // xproj + t*128*2048
    int lane = threadIdx.x & 63, w = threadIdx.x >> 6;
    int b0 = blockIdx.x * 32 + (w & 1) * 16;   // batch rows  (gridDim.x = 4)
    int j0 = blockIdx.y * 32 + (w >> 1) * 16;  // hidden cols (gridDim.y = 16)
    f32x4 ai = {}, af = {}, ag = {}, ao = {};
    #pragma unroll 4
    for (int k = 0; k < HID; k += 32) {
        bf16x8 a = frag16(hprev, b0, HID, k, lane);
        ai = MFMA16(a, frag16(Whh, j0, HID, k, lane), ai, 0, 0, 0);
        af = MFMA16(a, frag16(Whh, HID + j0, HID, k, lane), af, 0, 0, 0);
        ag = MFMA16(a, frag16(Whh, 2 * HID + j0, HID, k, lane), ag, 0, 0, 0);
        ao = MFMA16(a, frag16(Whh, 3 * HID + j0, HID, k, lane), ao, 0, 0, 0);
    }
    int j = j0 + (lane & 15);
    #pragma unroll
    for (int r = 0; r < 4; r++) {
        int b = b0 + ((lane >> 4) << 2) + r;
        const float* xrow = xp + (size_t)b * GATES;
        float iv = ai[r] + xrow[j];
        float fv = af[r] + xrow[HID + j];
        float gv = ag[r] + xrow[2 * HID + j];
        float ov = ao[r] + xrow[3 * HID + j];
        float c_old = cbuf[b * HID + j];
        float c_new = sigm(fv) * c_old + sigm(iv) * tanh_f(gv);
        cbuf[b * HID + j] = c_new;
        hnext[b * HID + j] = (bf16_t)(sigm(ov) * tanh_f(c_new));
    }
}

// ---------------- output GEMM: h[128,512] x Wout^T[512->2048] + b_out ----------------
__global__ __launch_bounds__(256) void k_out(
    const bf16_t* __restrict__ h,      // [128][512] bf16
    const bf16_t* __restrict__ Wout,   // [2048][512] bf16
    const float* __restrict__ bout,
    float* __restrict__ out) {         // [128][2048] f32
    int lane = threadIdx.x & 63, w = threadIdx.x >> 6;
    int r0 = blockIdx.x * 32 + (w & 1) * 16;      // batch rows (gridDim.x = 4)
    int g0 = blockIdx.y * 128 + (w >> 1) * 64;    // out cols (gridDim.y = 16)
    f32x4 acc[4] = {};
    #pragma unroll 4
    for (int k = 0; k < HID; k += 32) {
        bf16x8 a = frag16(h, r0, HID, k, lane);
        #pragma unroll
        for (int t = 0; t < 4; t++) {
            bf16x8 b = frag16(Wout, g0 + 16 * t, HID, k, lane);
            acc[t] = MFMA16(a, b, acc[t], 0, 0, 0);
        }
    }
    #pragma unroll
    for (int t = 0; t < 4; t++) {
        int g = g0 + 16 * t + (lane & 15);
        float bs = bout[g];
        #pragma unroll
        for (int r = 0; r < 4; r++) {
            int row = r0 + ((lane >> 4) << 2) + r;
            out[(size_t)row * NFEAT + g] = acc[t][r] + bs;
        }
    }
}

extern "C" void kernel_launch(void* const* d_in, const int* in_sizes, int n_in,
                              void* d_out, int out_size, void* d_ws, size_t ws_size,
                              hipStream_t stream) {
    const int*   m       = (const int*)d_in[0];
    // d_in[1] = images (unused by reference)
    const float* emb_tab = (const float*)d_in[2];
    const float* W_ih    = (const float*)d_in[3];
    const float* W_hh    = (const float*)d_in[4];
    const float* b_ih    = (const float*)d_in[5];
    const float* b_hh    = (const float*)d_in[6];
    const float* W_out   = (const float*)d_in[7];
    const float* b_out   = (const float*)d_in[8];

    char* ws = (char*)d_ws;
    // offsets (bytes); all 16B-aligned
    float*  xproj   = (float*) (ws + 0);          // 64*128*2048*4  = 67108864
    bf16_t* emb_b   = (bf16_t*)(ws + 67108864);   // 2097152*2      = 4194304
    bf16_t* wih_b   = (bf16_t*)(ws + 71303168);   // 524288*2       = 1048576
    bf16_t* whh_b   = (bf16_t*)(ws + 72351744);   // 1048576*2      = 2097152
    bf16_t* wout_b  = (bf16_t*)(ws + 74448896);   // 1048576*2      = 2097152
    bf16_t* h0      = (bf16_t*)(ws + 76546048);   // 65536*2        = 131072
    bf16_t* h1      = (bf16_t*)(ws + 76677120);   // 131072
    float*  cbuf    = (float*) (ws + 76808192);   // 65536*4        = 262144
    float*  biassum = (float*) (ws + 77070336);   // 8192

    k_prep<<<dim3(2048), dim3(256), 0, stream>>>(W_ih, W_hh, W_out, b_ih, b_hh, m, emb_tab,
                                                 wih_b, whh_b, wout_b, biassum, emb_b,
                                                 h0, h1, cbuf);

    k_xproj<<<dim3(256, 16), dim3(256), 0, stream>>>(emb_b, wih_b, biassum, xproj);

    for (int t = 0; t < TSTEPS; ++t) {
        const bf16_t* hp = (t & 1) ? h1 : h0;
        bf16_t*       hn = (t & 1) ? h0 : h1;
        k_step<<<dim3(4, 16), dim3(256), 0, stream>>>(hp, hn, cbuf, whh_b,
                                                      xproj + (size_t)t * BATCH * GATES);
    }
    // final h lives in h0 (t=63 writes h0)
    k_out<<<dim3(4, 16), dim3(256), 0, stream>>>(h0, wout_b, b_out, (float*)d_out);
}

// Round 2
// 846.553 us; speedup vs baseline: 1.0483x; 1.0483x over previous
//
#include <hip/hip_runtime.h>
#include <hip/hip_bf16.h>

// Problem constants
#define BATCH 128
#define TSTEPS 64
#define EMB 256
#define HID 512
#define GATES 2048   // 4*HID
#define NFEAT 2048
#define VOCAB 50000
#define NBLK 64      // persistent recurrence blocks (co-resident: 64 <= 256 CUs, 83KB LDS -> 1/CU)

typedef __bf16 bf16_t;
typedef __attribute__((ext_vector_type(8))) __bf16 bf16x8;
typedef __attribute__((ext_vector_type(4))) float f32x4;

#define MFMA16 __builtin_amdgcn_mfma_f32_16x16x32_bf16

// A/B fragment from row-major global: lane l -> row = row0 + (l&15), k = k0 + (l>>4)*8.
// Consistent bijective K-permutation for A and B cancels in GEMM; C/D mapping is the verified one.
__device__ __forceinline__ bf16x8 frag16(const bf16_t* __restrict__ base, int row0, int stride,
                                         int k0, int lane) {
    return *(const bf16x8*)(base + (size_t)(row0 + (lane & 15)) * stride + k0 + ((lane >> 4) << 3));
}

__device__ __forceinline__ float sigm(float x) { return 1.f / (1.f + __expf(-x)); }
__device__ __forceinline__ float tanh_f(float x) { return 1.f - 2.f / (__expf(2.f * x) + 1.f); }

// ---------------- prep: weights->bf16, gather emb (t-major), zero h init + barrier counter ----
__global__ __launch_bounds__(256) void k_prep(
    const float* __restrict__ Wih, const float* __restrict__ Whh, const float* __restrict__ Wout,
    const float* __restrict__ bih, const float* __restrict__ bhh,
    const int* __restrict__ m, const float* __restrict__ emb_tab,
    bf16_t* __restrict__ wih_b, bf16_t* __restrict__ whh_b, bf16_t* __restrict__ wout_b,
    float* __restrict__ biassum, bf16_t* __restrict__ emb_b,
    bf16_t* __restrict__ h_init, unsigned* __restrict__ cnt) {
    const int N1 = GATES * EMB;          // Wih
    const int N2 = GATES * HID;          // Whh
    const int N3 = NFEAT * HID;          // Wout
    const int N4 = GATES;                // bias sum
    const int N5 = BATCH * TSTEPS * EMB; // gather (t-major rows)
    const int N6 = BATCH * HID;          // h_init zero
    const long total = (long)N1 + N2 + N3 + N4 + N5 + N6 + 1;
    for (long i = (long)blockIdx.x * blockDim.x + threadIdx.x; i < total;
         i += (long)gridDim.x * blockDim.x) {
        long x = i;
        if (x < N1) { wih_b[x] = (bf16_t)Wih[x]; continue; } x -= N1;
        if (x < N2) { whh_b[x] = (bf16_t)Whh[x]; continue; } x -= N2;
        if (x < N3) { wout_b[x] = (bf16_t)Wout[x]; continue; } x -= N3;
        if (x < N4) { biassum[x] = bih[x] + bhh[x]; continue; } x -= N4;
        if (x < N5) {
            int e = (int)(x & (EMB - 1));
            int rt = (int)(x >> 8);            // rt = t*128 + b  (t-major)
            int t = rt >> 7, b = rt & 127;
            int tok = m[b * TSTEPS + t];
            emb_b[x] = (bf16_t)emb_tab[(size_t)tok * EMB + e];
            continue;
        } x -= N5;
        if (x < N6) { h_init[x] = (bf16_t)0.f; continue; } x -= N6;
        cnt[0] = 0u;
    }
}

// ---------------- x_proj GEMM: emb[8192,256] x Wih^T -> xproj f32 [t*128+b][2048] (+bias) -----
__global__ __launch_bounds__(256) void k_xproj(
    const bf16_t* __restrict__ A,     // emb_b [8192][256], row = t*128+b
    const bf16_t* __restrict__ Wih,   // [2048][256]
    const float* __restrict__ biassum,
    float* __restrict__ xproj) {      // [8192][2048], row = t*128+b  (contiguous writes)
    int lane = threadIdx.x & 63, w = threadIdx.x >> 6;
    int r0 = blockIdx.x * 32 + (w & 1) * 16;       // row tile
    int g0 = blockIdx.y * 128 + (w >> 1) * 64;     // col tile
    f32x4 acc[4] = {};
    #pragma unroll
    for (int k = 0; k < EMB; k += 32) {
        bf16x8 a = frag16(A, r0, EMB, k, lane);
        #pragma unroll
        for (int t = 0; t < 4; t++) {
            bf16x8 b = frag16(Wih, g0 + 16 * t, EMB, k, lane);
            acc[t] = MFMA16(a, b, acc[t], 0, 0, 0);
        }
    }
    #pragma unroll
    for (int t = 0; t < 4; t++) {
        int g = g0 + 16 * t + (lane & 15);
        float bs = biassum[g];
        #pragma unroll
        for (int r = 0; r < 4; r++) {
            int row = r0 + ((lane >> 4) << 2) + r;
            xproj[(size_t)row * GATES + g] = acc[t][r] + bs;
        }
    }
}

// ---------------- grid barrier (device-scope, per-XCD L2 handled by agent fences) ----------
__device__ __forceinline__ void gridbar(unsigned* cnt, unsigned target) {
    __syncthreads();   // includes s_waitcnt vmcnt(0): all waves' h-stores are in L2 before tid0 proceeds
    if (threadIdx.x == 0) {
        __hip_atomic_fetch_add(cnt, 1u, __ATOMIC_RELEASE, __HIP_MEMORY_SCOPE_AGENT);  // wbL2 + add at LLC
        while (__hip_atomic_load(cnt, __ATOMIC_RELAXED, __HIP_MEMORY_SCOPE_AGENT) < target)
            __builtin_amdgcn_s_sleep(1);
        __builtin_amdgcn_fence(__ATOMIC_ACQUIRE, "agent");  // invalidate L1/L2 so h reads are fresh
    }
    __syncthreads();
}

// ---------------- persistent recurrence: all 64 steps in one kernel ----------------
// Block b: hidden strip s = b>>1 (16 cols, j0=s*16), batch half = b&1 (64 rows).
// Wave w computes gate w for all 64 rows (4 row-tiles x K=512 -> 64 MFMA/step).
// Whh strip LDS-resident (XOR-swizzled, T2). c in registers. h double-buffered in ws.
__global__ __launch_bounds__(256, 1) void k_rnn(
    const float* __restrict__ xpf,    // [8192][2048] f32, row = t*128+b
    const bf16_t* __restrict__ whh,   // [2048][512] bf16
    bf16_t* __restrict__ hbuf,        // [2][128][512] bf16; hbuf[1] zeroed by prep
    unsigned* __restrict__ cnt) {
    __shared__ bf16_t whh_s[4 * 16 * 512];  // 64KB, swizzled: byte ^= ((row&7)<<4)
    __shared__ float  gex[4][64][17];       // gate exchange, padded
    const int tid = threadIdx.x;
    const int lane = tid & 63, w = tid >> 6;
    const int jj = lane & 15, q = lane >> 4;
    const int strip = blockIdx.x >> 1;
    const int half  = blockIdx.x & 1;
    const int j0 = strip * 16;
    const int r0 = half * 64;

    // --- stage Whh strip (rows g*512 + j0 + jj, 1KB each) into LDS, swizzled ---
    for (int it = 0; it < 16; ++it) {
        int chunk = it * 256 + tid;          // 0..4095 sixteen-byte chunks
        int row = chunk >> 6;                // 0..63  (= g*16 + jjr)
        int off = (chunk & 63) << 4;         // byte offset within 1KB row
        int g = row >> 4, jjr = row & 15;
        uint4 v = *(const uint4*)((const char*)whh +
                    ((size_t)(g * HID + j0 + jjr) * HID) * 2 + off);
        int soff = off ^ ((jjr & 7) << 4);
        *(uint4*)((char*)whh_s + row * 1024 + soff) = v;
    }
    __syncthreads();

    float c[4] = {0.f, 0.f, 0.f, 0.f};   // cell state: rows r0 + w*16 + q*4 + rr, col j0+jj
    unsigned tgt = 0;

    for (int t = 0; t < TSTEPS; ++t) {
        const bf16_t* hp = hbuf + (size_t)((t + 1) & 1) * BATCH * HID;
        bf16_t*       hn = hbuf + (size_t)(t & 1) * BATCH * HID;

        // prefetch xproj values (independent of h; latency hides under MFMA)
        float xv[4][4];
        const float* xbase = xpf + ((size_t)t * BATCH + r0 + w * 16 + q * 4) * GATES + j0 + jj;
        #pragma unroll
        for (int rr = 0; rr < 4; ++rr)
            #pragma unroll
            for (int g = 0; g < 4; ++g)
                xv[rr][g] = xbase[(size_t)rr * GATES + g * HID];

        // --- gates GEMM: gate w, 64 rows x 16 cols, K=512 ---
        f32x4 acc[4] = {};
        #pragma unroll 4
        for (int k = 0; k < HID; k += 32) {
            // B-frag from swizzled LDS: row jj of gate-w strip
            int boff = (k * 2 + q * 16) ^ ((jj & 7) << 4);
            bf16x8 b = *(const bf16x8*)((const char*)whh_s + w * 16384 + jj * 1024 + boff);
            #pragma unroll
            for (int mr = 0; mr < 4; ++mr) {
                bf16x8 a = frag16(hp, r0 + mr * 16, HID, k, lane);
                acc[mr] = MFMA16(a, b, acc[mr], 0, 0, 0);
            }
        }

        // --- exchange gates via LDS ---
        #pragma unroll
        for (int mr = 0; mr < 4; ++mr)
            #pragma unroll
            for (int rr = 0; rr < 4; ++rr)
                gex[w][mr * 16 + q * 4 + rr][jj] = acc[mr][rr];
        __syncthreads();

        // --- cell update: this thread owns rows rloc = w*16 + q*4 + rr, col jj ---
        #pragma unroll
        for (int rr = 0; rr < 4; ++rr) {
            int rloc = w * 16 + q * 4 + rr;
            float iv = gex[0][rloc][jj] + xv[rr][0];
            float fv = gex[1][rloc][jj] + xv[rr][1];
            float gv = gex[2][rloc][jj] + xv[rr][2];
            float ov = gex[3][rloc][jj] + xv[rr][3];
            float cn = sigm(fv) * c[rr] + sigm(iv) * tanh_f(gv);
            c[rr] = cn;
            hn[(size_t)(r0 + rloc) * HID + j0 + jj] = (bf16_t)(sigm(ov) * tanh_f(cn));
        }

        tgt += NBLK;
        gridbar(cnt, tgt);   // internal syncthreads also protects gex reuse
    }
}

// ---------------- output GEMM: h[128,512] x Wout^T + b_out -> out f32 [128][2048] ------------
__global__ __launch_bounds__(256) void k_out(
    const bf16_t* __restrict__ h,      // final h = hbuf[1]
    const bf16_t* __restrict__ Wout,   // [2048][512] bf16
    const float* __restrict__ bout,
    float* __restrict__ out) {
    int lane = threadIdx.x & 63, w = threadIdx.x >> 6;
    int r0 = blockIdx.x * 32 + (w & 1) * 16;
    int g0 = blockIdx.y * 128 + (w >> 1) * 64;
    f32x4 acc[4] = {};
    #pragma unroll 4
    for (int k = 0; k < HID; k += 32) {
        bf16x8 a = frag16(h, r0, HID, k, lane);
        #pragma unroll
        for (int t = 0; t < 4; t++) {
            bf16x8 b = frag16(Wout, g0 + 16 * t, HID, k, lane);
            acc[t] = MFMA16(a, b, acc[t], 0, 0, 0);
        }
    }
    #pragma unroll
    for (int t = 0; t < 4; t++) {
        int g = g0 + 16 * t + (lane & 15);
        float bs = bout[g];
        #pragma unroll
        for (int r = 0; r < 4; r++) {
            int row = r0 + ((lane >> 4) << 2) + r;
            out[(size_t)row * NFEAT + g] = acc[t][r] + bs;
        }
    }
}

extern "C" void kernel_launch(void* const* d_in, const int* in_sizes, int n_in,
                              void* d_out, int out_size, void* d_ws, size_t ws_size,
                              hipStream_t stream) {
    const int*   m       = (const int*)d_in[0];
    // d_in[1] = images (unused by reference)
    const float* emb_tab = (const float*)d_in[2];
    const float* W_ih    = (const float*)d_in[3];
    const float* W_hh    = (const float*)d_in[4];
    const float* b_ih    = (const float*)d_in[5];
    const float* b_hh    = (const float*)d_in[6];
    const float* W_out   = (const float*)d_in[7];
    const float* b_out   = (const float*)d_in[8];

    char* ws = (char*)d_ws;
    float*    xpf     = (float*)   (ws + 0);          // 8192*2048*4 = 67108864
    bf16_t*   emb_b   = (bf16_t*)  (ws + 67108864);   // 2097152*2   = 4194304
    bf16_t*   wih_b   = (bf16_t*)  (ws + 71303168);   // 1048576
    bf16_t*   whh_b   = (bf16_t*)  (ws + 72351744);   // 2097152
    bf16_t*   wout_b  = (bf16_t*)  (ws + 74448896);   // 2097152
    bf16_t*   hbuf    = (bf16_t*)  (ws + 76546048);   // 2*65536*2   = 262144
    float*    biassum = (float*)   (ws + 76808192);   // 8192
    unsigned* cnt     = (unsigned*)(ws + 76816384);   // 4

    k_prep<<<dim3(2048), dim3(256), 0, stream>>>(W_ih, W_hh, W_out, b_ih, b_hh, m, emb_tab,
                                                 wih_b, whh_b, wout_b, biassum, emb_b,
                                                 hbuf + BATCH * HID /*h_init = hbuf[1]*/, cnt);

    k_xproj<<<dim3(256, 16), dim3(256), 0, stream>>>(emb_b, wih_b, biassum, xpf);

    k_rnn<<<dim3(NBLK), dim3(256), 0, stream>>>(xpf, whh_b, hbuf, cnt);

    // t=63 writes hbuf[1] -> final h
    k_out<<<dim3(4, 16), dim3(256), 0, stream>>>(hbuf + BATCH * HID, wout_b, b_out, (float*)d_out);
}